// Round 12
// baseline (336.892 us; speedup 1.0000x reference)
//
#include <hip/hip_runtime.h>
#include <math.h>

#define B_  8
#define CIN 3
#define HIN 256
#define WIN 256
#define CMID 16
#define HMID 128
#define WMID 128
#define DM 256
#define L_ 4096
#define DI 512
#define NH 8
#define HD 64
#define NS 128
#define KC 4
#define CONVDIM 768
#define PROJ 1288
#define NPADIN 1408
#define MTOK (B_*L_)
#define QCH 128          // chunk length (SSD)
#define NCH 32           // number of chunks

typedef unsigned short bf16;
typedef __attribute__((ext_vector_type(8))) short bf16x8;
typedef __attribute__((ext_vector_type(4))) float f32x4;

__device__ inline float bf2f(bf16 u) { return __uint_as_float(((unsigned int)u) << 16); }
__device__ inline bf16 f2bf(float f) {
  unsigned int x = __float_as_uint(f);
  return (bf16)((x + 0x7fffu + ((x >> 16) & 1u)) >> 16);
}
__device__ inline unsigned int pack2bf(float a, float b) {
  return (unsigned int)f2bf(a) | ((unsigned int)f2bf(b) << 16);
}

// ---------------- conv 3x3 stride 2 pad 1 ----------------
__global__ void k_conv1(const float* __restrict__ x, const float* __restrict__ w,
                        const float* __restrict__ bias, float* __restrict__ out) {
  int idx = blockIdx.x*256 + threadIdx.x;
  if (idx >= B_*CMID*HMID*WMID) return;
  int xo = idx & 127, yo = (idx>>7)&127, co = (idx>>14)&15, b = idx>>18;
  float acc = bias[co];
  const float* xb = x + (size_t)b*CIN*HIN*WIN;
  const float* wc = w + co*CIN*9;
  #pragma unroll
  for (int ci=0; ci<CIN; ci++)
    #pragma unroll
    for (int ky=0; ky<3; ky++) {
      int yi = 2*yo - 1 + ky;
      if (yi < 0 || yi >= HIN) continue;
      #pragma unroll
      for (int kx=0; kx<3; kx++) {
        int xi = 2*xo - 1 + kx;
        if (xi < 0 || xi >= WIN) continue;
        acc += xb[(ci*HIN + yi)*WIN + xi] * wc[(ci*3+ky)*3+kx];
      }
    }
  out[idx] = acc;
}

// ---------------- BN stats stage A ----------------
__global__ __launch_bounds__(256) void k_bnstatsA(const float* __restrict__ h, float2* __restrict__ part) {
  int blk = blockIdx.x;
  const float4* base = (const float4*)(h + ((size_t)(blk>>2))*16384 + (blk&3)*4096);
  int tid = threadIdx.x;
  float s=0.f, s2=0.f;
  #pragma unroll
  for (int i=0;i<4;i++){
    float4 v = base[i*256 + tid];
    s += v.x+v.y+v.z+v.w;
    s2 += v.x*v.x + v.y*v.y + v.z*v.z + v.w*v.w;
  }
  #pragma unroll
  for (int off=1; off<64; off<<=1) { s += __shfl_xor(s, off); s2 += __shfl_xor(s2, off); }
  __shared__ float sb[2][4];
  if ((tid&63)==0){ sb[0][tid>>6]=s; sb[1][tid>>6]=s2; }
  __syncthreads();
  if (tid==0) part[blk] = make_float2(sb[0][0]+sb[0][1]+sb[0][2]+sb[0][3],
                                      sb[1][0]+sb[1][1]+sb[1][2]+sb[1][3]);
}

// ---------------- BN stats stage B ----------------
__global__ void k_bnstatsB(const float2* __restrict__ part, float* __restrict__ stats) {
  int lane = threadIdx.x;
  int c = lane >> 2, j0 = lane & 3;
  float s=0.f, s2=0.f;
  #pragma unroll
  for (int j=j0; j<32; j+=4){
    int b = j >> 2, chunk = j & 3;
    float2 p = part[(b*16+c)*4 + chunk];
    s += p.x; s2 += p.y;
  }
  s += __shfl_xor(s,1); s2 += __shfl_xor(s2,1);
  s += __shfl_xor(s,2); s2 += __shfl_xor(s2,2);
  if (j0==0){
    const float inv = 1.f/131072.f;
    float mean = s*inv;
    float var  = s2*inv - mean*mean;
    stats[c]      = mean;
    stats[16 + c] = rsqrtf(var + 1e-5f);
  }
}

// ---------------- patch conv 2x2 s2 (+fused BN+GELU) + bias + sincos -> tok ----------------
__global__ __launch_bounds__(256) void k_patch(const float* __restrict__ h, const float* __restrict__ pw,
                       const float* __restrict__ pb, const float* __restrict__ stats,
                       const float* __restrict__ gamma, const float* __restrict__ beta,
                       bf16* __restrict__ tok) {
  int grp = blockIdx.x;
  int b = grp >> 9, g8 = grp & 511;
  int g0 = g8 << 3;
  int gy = g0 >> 6, gx0 = g0 & 63;
  __shared__ float sh[8][64];
  int tid = threadIdx.x;
  {
    int tk = tid >> 5, jj = (tid & 31)*2;
    int ci = jj >> 2, p = (jj >> 1) & 1;
    const float* src = &h[((size_t)(b*CMID+ci)*HMID + 2*gy+p)*WMID + 2*(gx0+tk)];
    float2 xv = *(const float2*)src;
    float mean = stats[ci], rstd = stats[16+ci];
    float sc = rstd*gamma[ci], be = beta[ci] - mean*sc;
    float v0 = xv.x*sc + be;
    float v1 = xv.y*sc + be;
    v0 = 0.5f*v0*(1.f + erff(v0*0.70710678118654752f));
    v1 = 0.5f*v1*(1.f + erff(v1*0.70710678118654752f));
    sh[tk][jj] = v0; sh[tk][jj+1] = v1;
  }
  __syncthreads();
  int d = tid;
  float wr[64];
  #pragma unroll
  for (int i4=0;i4<16;i4++) *(float4*)&wr[i4*4] = *(const float4*)&pw[d*64 + i4*4];
  float bias = pb[d];
  int i = d & 63;
  float omega = expf(-(float)i * (9.210340371976184f/64.f));
  #pragma unroll
  for (int tk=0;tk<8;tk++){
    float acc = bias;
    #pragma unroll
    for (int j=0;j<64;j++) acc = fmaf(sh[tk][j], wr[j], acc);
    float gv = (d < 128) ? (float)(gx0+tk) : (float)gy;
    float ph = gv * omega;
    float pos = (d & 64) ? __cosf(ph) : __sinf(ph);
    tok[((size_t)((b<<12) + g0 + tk))*DM + d] = f2bf(acc + pos);
  }
}

// ---------------- weight f32 -> bf16 (with zero-padding to Npad rows) ----------------
__global__ void k_cvtw(const float* __restrict__ src, bf16* __restrict__ dst,
                       int N, int kshift, int total) {
  int idx = blockIdx.x*256 + threadIdx.x;
  if (idx >= total) return;
  int n = idx >> kshift;
  dst[idx] = (n < N) ? f2bf(src[idx]) : (bf16)0;
}

// ---------------- MFMA bf16 GEMM, 256x128 tile, 512 thr, swapped, LDS-coalesced epilogue ----------------
template<int EPI>
__global__ __launch_bounds__(512) void k_mgemm(
    const bf16* __restrict__ A, const bf16* __restrict__ Bw, int K,
    bf16* __restrict__ o_z, bf16* __restrict__ o_x,
    bf16* __restrict__ o_y, const bf16* __restrict__ res,
    const float* __restrict__ dt_bias, const float* __restrict__ A_log,
    float* __restrict__ dtv, float* __restrict__ dAv,
    float* __restrict__ o_f, const float* __restrict__ fbias) {
  __shared__ __align__(16) char smem[49152];
  bf16* sA = (bf16*)smem;                 // 2 bufs x 256x32 = 32KB
  bf16* sB = (bf16*)(smem + 32768);       // 2 bufs x 128x32 = 16KB
  bf16* sT = (bf16*)smem;                 // 256x72 bf16 = 36KB, reused post-loop
  int tid = threadIdx.x;
  int lane = tid & 63, wid = tid >> 6;     // 8 waves
  int wr = wid >> 1, wc = wid & 1;         // wr: m tile (4x64), wc: n half (2x64)
  int m0 = blockIdx.x*256, n0 = blockIdx.y*128;
  int nk = K >> 5;

  f32x4 acc[4][4];
  #pragma unroll
  for (int i=0;i<4;i++)
    #pragma unroll
    for (int j=0;j<4;j++)
      acc[i][j] = (f32x4){0.f,0.f,0.f,0.f};

  auto stage = [&](int buf, int ks){
    int kk = ks << 5;
    #pragma unroll
    for (int i=0;i<2;i++){
      int j = i*512 + tid;
      int row = j >> 2, cc = j & 3;
      int kg = cc ^ (row & 3);
      unsigned ldsoff = (unsigned)(buf*16384 + (i*512 + wid*64) * 16);
      __builtin_amdgcn_global_load_lds(
        (const __attribute__((address_space(1))) void*)(A + (size_t)(m0+row)*K + kk + kg*8),
        (__attribute__((address_space(3))) void*)((char*)sA + ldsoff), 16, 0, 0);
    }
    {
      int row = tid >> 2, cc = tid & 3;
      int kg = cc ^ (row & 3);
      unsigned ldsoff = (unsigned)(buf*8192 + (wid*64) * 16);
      __builtin_amdgcn_global_load_lds(
        (const __attribute__((address_space(1))) void*)(Bw + (size_t)(n0+row)*K + kk + kg*8),
        (__attribute__((address_space(3))) void*)((char*)sB + ldsoff), 16, 0, 0);
    }
  };

  int r = lane & 15, q = lane >> 4;
  int kgo = (q ^ (r & 3)) << 3;

  stage(0, 0);
  for (int ks=0; ks<nk; ++ks){
    int cur = ks & 1;
    __syncthreads();
    if (ks+1 < nk) stage(cur^1, ks+1);
    bf16x8 af[4], bfv[4];
    #pragma unroll
    for (int a=0;a<4;a++){
      int rown = wc*64 + a*16 + r;
      af[a] = *(const bf16x8*)&sB[cur*4096 + rown*32 + kgo];
    }
    #pragma unroll
    for (int bfr=0;bfr<4;bfr++){
      int rowm = wr*64 + bfr*16 + r;
      bfv[bfr] = *(const bf16x8*)&sA[cur*8192 + rowm*32 + kgo];
    }
    #pragma unroll
    for (int a=0;a<4;a++)
      #pragma unroll
      for (int bfr=0;bfr<4;bfr++)
        acc[a][bfr] = __builtin_amdgcn_mfma_f32_16x16x32_bf16(af[a], bfv[bfr], acc[a][bfr], 0, 0, 0);
  }

  // ---- dt tile (EPI0, n0 == 1280): scalar routing only, skip transpose ----
  if (EPI == 0 && n0 >= DI + CONVDIM) {
    #pragma unroll
    for (int a=0;a<4;a++){
      int n4 = n0 + wc*64 + a*16 + q*4;
      if (n4 >= PROJ) continue;
      #pragma unroll
      for (int bfr=0;bfr<4;bfr++){
        int m = m0 + wr*64 + bfr*16 + r;
        f32x4 v = acc[a][bfr];
        #pragma unroll
        for (int rr=0;rr<4;rr++){
          int hh = n4 + rr - (DI + CONVDIM);
          if (hh < NH){
            float xv = v[rr] + dt_bias[hh];
            float dt = (xv > 20.f) ? xv : log1pf(expf(xv));
            dtv[(size_t)m*NH + hh] = dt;
            dAv[(size_t)m*NH + hh] = expf(-expf(A_log[hh]) * dt);
          }
        }
      }
    }
    return;
  }
  // ---- final-layer pixel shuffle (EPI2): scalar (64 cols only) ----
  if (EPI == 2) {
    #pragma unroll
    for (int a=0;a<4;a++){
      int n4 = n0 + wc*64 + a*16 + q*4;
      #pragma unroll
      for (int bfr=0;bfr<4;bfr++){
        int m = m0 + wr*64 + bfr*16 + r;
        f32x4 v = acc[a][bfr];
        #pragma unroll
        for (int rr=0;rr<4;rr++){
          int n = n4 + rr;
          if (n < 64) {
            float vv = v[rr] + fbias[n];
            int b = m >> 12, g = m & 4095;
            int gy = g >> 6, gx = g & 63;
            int p = n >> 5, qq = (n>>4)&1, cc2 = n & 15;
            o_f[(((size_t)(b*CMID+cc2))*HMID + 2*gy+p)*WMID + (2*gx+qq)] = vv;
          }
        }
      }
    }
    return;
  }

  // ---- transpose-through-LDS coalesced epilogue (EPI0 z/x tiles, EPI1) ----
  #pragma unroll
  for (int h2=0; h2<2; ++h2){
    __syncthreads();
    if (wc == h2){
      #pragma unroll
      for (int a=0;a<4;a++){
        int nl = a*16 + q*4;
        #pragma unroll
        for (int bfr=0;bfr<4;bfr++){
          int ml = wr*64 + bfr*16 + r;
          f32x4 v = acc[a][bfr];
          *(uint2*)&sT[ml*72 + nl] = make_uint2(pack2bf(v[0],v[1]), pack2bf(v[2],v[3]));
        }
      }
    }
    __syncthreads();
    int ml = tid >> 1, ch = tid & 1;
    int m = m0 + ml;
    int ncol = n0 + h2*64 + ch*32;
    const bf16* src = &sT[ml*72 + ch*32];
    if (EPI == 0){
      bf16* dst = (n0 < DI) ? (o_z + (size_t)m*DI + ncol)
                            : (o_x + (size_t)m*CONVDIM + (ncol - DI));
      #pragma unroll
      for (int i4=0;i4<4;i4++)
        *(uint4*)(dst + i4*8) = *(const uint4*)(src + i4*8);
    } else {
      bf16* dst = o_y + (size_t)m*DM + ncol;
      const bf16* rsv = res + (size_t)m*DM + ncol;
      #pragma unroll
      for (int i4=0;i4<4;i4++){
        uint4 t = *(const uint4*)(src + i4*8);
        uint4 rv = *(const uint4*)(rsv + i4*8);
        unsigned tu[4]={t.x,t.y,t.z,t.w}, ru[4]={rv.x,rv.y,rv.z,rv.w};
        unsigned ou[4];
        #pragma unroll
        for (int k2=0;k2<4;k2++){
          float a0 = bf2f((bf16)(tu[k2]&0xffffu)) + bf2f((bf16)(ru[k2]&0xffffu));
          float a1 = bf2f((bf16)(tu[k2]>>16))     + bf2f((bf16)(ru[k2]>>16));
          ou[k2] = pack2bf(a0,a1);
        }
        *(uint4*)(dst + i4*8) = make_uint4(ou[0],ou[1],ou[2],ou[3]);
      }
    }
  }
}

// ---------------- causal depthwise conv1d (KC=4) + bias + silu ----------------
__global__ __launch_bounds__(256) void k_conv1d(const bf16* __restrict__ xpre, const float* __restrict__ cw,
                         const float* __restrict__ cb, bf16* __restrict__ xbc) {
  int idx = blockIdx.x*256 + threadIdx.x;
  int gch = idx % 96;
  int tb  = idx / 96;
  int ch0 = gch*8;
  int bl0 = tb*8;
  int l0 = bl0 & (L_-1);
  float wv[32];
  #pragma unroll
  for (int i=0;i<8;i++) *(float4*)&wv[i*4] = *(const float4*)&cw[ch0*KC + i*4];
  float bs[8];
  *(float4*)&bs[0] = *(const float4*)&cb[ch0];
  *(float4*)&bs[4] = *(const float4*)&cb[ch0+4];
  uint4 rows[11];
  #pragma unroll
  for (int j=0;j<11;j++){
    int lk = l0 - 3 + j;
    if (lk < 0) rows[j] = make_uint4(0u,0u,0u,0u);
    else rows[j] = *(const uint4*)(xpre + ((size_t)bl0 - 3 + j)*CONVDIM + ch0);
  }
  #pragma unroll
  for (int t=0;t<8;t++){
    float acc[8];
    #pragma unroll
    for (int i=0;i<8;i++) acc[i] = bs[i];
    #pragma unroll
    for (int k=0;k<KC;k++){
      uint4 u = rows[t+k];
      unsigned uu[4]={u.x,u.y,u.z,u.w};
      #pragma unroll
      for (int c2=0;c2<4;c2++){
        float lo = __uint_as_float(uu[c2]<<16);
        float hi = __uint_as_float(uu[c2]&0xffff0000u);
        acc[c2*2]   = fmaf(wv[(c2*2)*4 + k],   lo, acc[c2*2]);
        acc[c2*2+1] = fmaf(wv[(c2*2+1)*4 + k], hi, acc[c2*2+1]);
      }
    }
    unsigned ou[4];
    #pragma unroll
    for (int c2=0;c2<4;c2++){
      float v0 = acc[c2*2], v1 = acc[c2*2+1];
      v0 = v0 / (1.f + __expf(-v0));
      v1 = v1 / (1.f + __expf(-v1));
      ou[c2] = pack2bf(v0, v1);
    }
    *(uint4*)(xbc + (size_t)(bl0+t)*CONVDIM + ch0) = make_uint4(ou[0],ou[1],ou[2],ou[3]);
  }
}

// ================= SSD pass 1: 80KB LDS (2 blocks/CU), in-place BT, late DX =================
__global__ __launch_bounds__(512) void k_ssd1(const bf16* __restrict__ xbc,
    const float* __restrict__ dtv, const float* __restrict__ A_log,
    bf16* __restrict__ ys, bf16* __restrict__ Sst) {
  int blk = blockIdx.x;
  int c = blk & (NCH-1), h = (blk>>5)&7, b = blk>>8;
  int tid = threadIdx.x;
  int lane = tid & 63, wid = tid >> 6;     // 8 waves
  int r = lane & 15, q = lane >> 4;
  size_t rowbase = (size_t)b*L_ + (size_t)c*QCH;
  float eA = __expf(A_log[h]);

  __shared__ __align__(16) char smem[81920];
  bf16* sB  = (bf16*)smem;
  bf16* sC  = (bf16*)(smem + 32768);
  bf16* sDX = (bf16*)(smem + 65536);
  float* fDT = (float*)(smem + 65536);
  float* fL  = fDT + 128;
  float* fWS = fL + 128;
  float* fWT = fWS + 128;

  #pragma unroll
  for (int i=0;i<8;i++){
    int id = i*512 + tid;
    int row = id >> 5, cg = id & 31;
    uint4 u = *(const uint4*)(xbc + (rowbase+row)*CONVDIM + DI + cg*8);
    if (cg < 16) *(uint4*)&sB[row*128 + ((cg ^ (row&15))<<3)] = u;
    else { int cg2 = cg-16; *(uint4*)&sC[row*128 + ((cg2 ^ (row&15))<<3)] = u; }
  }
  if (tid < 128) fDT[tid] = dtv[(rowbase+tid)*NH + h];
  __syncthreads();

  float inc = 0.f;
  if (tid < 128){
    inc = fDT[tid];
    #pragma unroll
    for (int off=1; off<64; off<<=1){
      float u = __shfl_up(inc, off);
      if (lane >= off) inc += u;
    }
    if (lane==63) fWT[wid] = inc;
  }
  __syncthreads();
  if (tid < 128){
    if (wid==1) inc += fWT[0];
    fL[tid] = inc;
  }

  int wr = wid >> 1, wc = wid & 1;
  f32x4 accG[2][4];
  #pragma unroll
  for (int i=0;i<2;i++)
    #pragma unroll
    for (int j=0;j<4;j++) accG[i][j] = (f32x4){0.f,0.f,0.f,0.f};
  #pragma unroll
  for (int ks=0; ks<4; ks++){
    bf16x8 af[2], bfv[4];
    #pragma unroll
    for (int mf=0;mf<2;mf++){
      int s = wr*32 + mf*16 + r;
      af[mf] = *(const bf16x8*)&sB[s*128 + (((ks*4+q) ^ (s&15))<<3)];
    }
    #pragma unroll
    for (int nf=0;nf<4;nf++){
      int t = wc*64 + nf*16 + r;
      bfv[nf] = *(const bf16x8*)&sC[t*128 + (((ks*4+q) ^ (t&15))<<3)];
    }
    #pragma unroll
    for (int mf=0;mf<2;mf++)
      #pragma unroll
      for (int nf=0;nf<4;nf++)
        accG[mf][nf] = __builtin_amdgcn_mfma_f32_16x16x32_bf16(af[mf], bfv[nf], accG[mf][nf], 0, 0, 0);
  }
  __syncthreads();

  bf16* sW = sC;
  #pragma unroll
  for (int mf=0;mf<2;mf++){
    int sb4 = wr*32 + mf*16 + q*4;
    int cb4 = sb4 >> 3, se4 = sb4 & 7;
    #pragma unroll
    for (int nf=0;nf<4;nf++){
      int t = wc*64 + nf*16 + r;
      float Lt = fL[t];
      float w[4];
      #pragma unroll
      for (int rr=0;rr<4;rr++){
        int s = sb4 + rr;
        float v = 0.f;
        if (s <= t) v = accG[mf][nf][rr] * fDT[s] * __expf(-eA*(Lt - fL[s]));
        w[rr] = v;
      }
      *(uint2*)&sW[t*128 + ((cb4 ^ (t&15))<<3) + se4] =
          make_uint2(pack2bf(w[0],w[1]), pack2bf(w[2],w[3]));
    }
  }
  if (tid < 128) fWS[tid] = fDT[tid]*__expf(-eA*(fL[127]-fL[tid]));
  __syncthreads();

  int nT = tid >> 2, sg = tid & 3;
  unsigned short vals[32];
  #pragma unroll
  for (int i8=0;i8<4;i8++){
    #pragma unroll
    for (int j=0;j<8;j++){
      int s = sg*32 + i8*8 + j;
      float bv = bf2f(sB[s*128 + (((nT>>3) ^ (s&15))<<3) + (nT&7)]);
      vals[i8*8+j] = f2bf(bv * fWS[s]);
    }
  }
  __syncthreads();

  #pragma unroll
  for (int i8=0;i8<4;i8++){
    int s8 = sg*4 + i8;
    *(uint4*)&sB[nT*128 + ((s8 ^ (nT&15))<<3)] = *(const uint4*)&vals[i8*8];
  }
  {
    int s0 = (tid >> 3)*2;
    int p0 = (tid & 7)*8;
    const bf16* x0 = xbc + (rowbase+s0)*CONVDIM + h*HD + p0;
    uint4 u0 = *(const uint4*)x0;
    uint4 u1 = *(const uint4*)(x0 + CONVDIM);
    unsigned a0[4]={u0.x,u0.y,u0.z,u0.w}, a1[4]={u1.x,u1.y,u1.z,u1.w};
    int cb2 = s0 >> 3, se = s0 & 7;
    #pragma unroll
    for (int jp=0;jp<4;jp++){
      unsigned w0=a0[jp], w1=a1[jp];
      unsigned lo = (w0 & 0xffffu) | (w1 << 16);
      unsigned hi = (w0 >> 16) | (w1 & 0xffff0000u);
      int pA = p0 + jp*2, pB = pA+1;
      *(unsigned*)&sDX[pA*128 + ((cb2 ^ (pA&15))<<3) + se] = lo;
      *(unsigned*)&sDX[pB*128 + ((cb2 ^ (pB&15))<<3) + se] = hi;
    }
  }
  __syncthreads();

  {
    int wrp = wid >> 2, wct = wid & 3;
    f32x4 acc2[2][2];
    #pragma unroll
    for (int i=0;i<2;i++){ acc2[i][0]=(f32x4){0.f,0.f,0.f,0.f}; acc2[i][1]=(f32x4){0.f,0.f,0.f,0.f}; }
    #pragma unroll
    for (int ks=0; ks<4; ks++){
      bf16x8 af[2], bfv[2];
      #pragma unroll
      for (int mf=0;mf<2;mf++){
        int p = wrp*32 + mf*16 + r;
        af[mf] = *(const bf16x8*)&sDX[p*128 + (((ks*4+q) ^ (p&15))<<3)];
      }
      #pragma unroll
      for (int nf=0;nf<2;nf++){
        int t = wct*32 + nf*16 + r;
        bfv[nf] = *(const bf16x8*)&sW[t*128 + (((ks*4+q) ^ (t&15))<<3)];
      }
      #pragma unroll
      for (int mf=0;mf<2;mf++)
        #pragma unroll
        for (int nf=0;nf<2;nf++)
          acc2[mf][nf] = __builtin_amdgcn_mfma_f32_16x16x32_bf16(af[mf], bfv[nf], acc2[mf][nf], 0, 0, 0);
    }
    #pragma unroll
    for (int mf=0;mf<2;mf++){
      int pb = wrp*32 + mf*16 + q*4;
      #pragma unroll
      for (int nf=0;nf<2;nf++){
        int t = wct*32 + nf*16 + r;
        f32x4 v = acc2[mf][nf];
        *(uint2*)(ys + (rowbase+t)*DI + h*HD + pb) =
            make_uint2(pack2bf(v[0],v[1]), pack2bf(v[2],v[3]));
      }
    }
  }
  {
    int wrn = wid >> 1, wcp = wid & 1;
    f32x4 acc3[2][2];
    #pragma unroll
    for (int i=0;i<2;i++){ acc3[i][0]=(f32x4){0.f,0.f,0.f,0.f}; acc3[i][1]=(f32x4){0.f,0.f,0.f,0.f}; }
    #pragma unroll
    for (int ks=0; ks<4; ks++){
      bf16x8 af[2], bfv[2];
      #pragma unroll
      for (int mf=0;mf<2;mf++){
        int n = wrn*32 + mf*16 + r;
        af[mf] = *(const bf16x8*)&sB[n*128 + (((ks*4+q) ^ (n&15))<<3)];
      }
      #pragma unroll
      for (int nf=0;nf<2;nf++){
        int p = wcp*32 + nf*16 + r;
        bfv[nf] = *(const bf16x8*)&sDX[p*128 + (((ks*4+q) ^ (p&15))<<3)];
      }
      #pragma unroll
      for (int mf=0;mf<2;mf++)
        #pragma unroll
        for (int nf=0;nf<2;nf++)
          acc3[mf][nf] = __builtin_amdgcn_mfma_f32_16x16x32_bf16(af[mf], bfv[nf], acc3[mf][nf], 0, 0, 0);
    }
    size_t sb = (((size_t)(b*NH+h))*NCH + c)*8192;
    #pragma unroll
    for (int mf=0;mf<2;mf++){
      int nb = wrn*32 + mf*16 + q*4;
      #pragma unroll
      for (int nf=0;nf<2;nf++){
        int p = wcp*32 + nf*16 + r;
        f32x4 v = acc3[mf][nf];
        *(uint2*)(Sst + sb + (size_t)p*128 + nb) =
            make_uint2(pack2bf(v[0],v[1]), pack2bf(v[2],v[3]));
      }
    }
  }
}

// ---------------- pass 2: prefix-combine chunk states ----------------
template<int NCHT, int QCHT>
__global__ __launch_bounds__(256) void k_scan2(bf16* __restrict__ Sst, const float* __restrict__ dAv) {
  constexpr int SEG = QCHT/16;
  int blk = blockIdx.x;
  int bh = blk>>2, q = blk&3;
  int b = bh>>3, h = bh&7;
  int tid = threadIdx.x;
  __shared__ float sP[NCHT];
  {
    int c = tid / SEG, seg = tid & (SEG-1);
    float prod = 1.f;
    size_t base = ((size_t)b*L_ + c*QCHT + seg*16)*NH + h;
    #pragma unroll
    for (int k=0;k<16;k++) prod *= dAv[base + (size_t)k*NH];
    #pragma unroll
    for (int off=1; off<SEG; off<<=1) prod *= __shfl_xor(prod, off);
    if (seg==0) sP[c] = prod;
  }
  __syncthreads();
  int e0 = q*2048 + tid*8;
  float acc[8];
  #pragma unroll
  for (int j=0;j<8;j++) acc[j]=0.f;
  size_t sbase = (size_t)bh*NCHT*8192 + e0;
  for (int c=0;c<NCHT;c++){
    bf16* ptr = Sst + sbase + (size_t)c*8192;
    uint4 u = *(const uint4*)ptr;
    unsigned int uu[4] = {u.x,u.y,u.z,u.w};
    float tv[8];
    #pragma unroll
    for (int k=0;k<4;k++){
      tv[2*k]   = __uint_as_float(uu[k]<<16);
      tv[2*k+1] = __uint_as_float(uu[k]&0xffff0000u);
    }
    uint4 o;
    o.x = pack2bf(acc[0],acc[1]); o.y = pack2bf(acc[2],acc[3]);
    o.z = pack2bf(acc[4],acc[5]); o.w = pack2bf(acc[6],acc[7]);
    asm volatile("s_waitcnt vmcnt(0)" ::: "memory");
    *(uint4*)ptr = o;
    float P = sP[c];
    #pragma unroll
    for (int j=0;j<8;j++) acc[j] = tv[j] + P*acc[j];
  }
}

// ================= SSD pass 3: Y += exp(-eA*L_t) * (C x I_c), swapped (b64 RMW) =================
__global__ __launch_bounds__(256) void k_ssd3(const bf16* __restrict__ xbc,
    const float* __restrict__ dtv, const float* __restrict__ A_log,
    const bf16* __restrict__ Sst, bf16* __restrict__ ys) {
  int blk = blockIdx.x;
  int c = blk & (NCH-1), h = (blk>>5)&7, b = blk>>8;
  int tid = threadIdx.x;
  int lane = tid & 63, wid = tid >> 6;
  int r = lane & 15, q = lane >> 4;
  size_t rowbase = (size_t)b*L_ + (size_t)c*QCH;
  float eA = __expf(A_log[h]);

  __shared__ __align__(16) bf16 sC[128*128];
  __shared__ float sDT[128];
  __shared__ float sAt[128];
  __shared__ float sWT[2];

  #pragma unroll
  for (int i=0;i<8;i++){
    int id = i*256 + tid;
    int row = id >> 4, cg = id & 15;
    uint4 u = *(const uint4*)(xbc + (rowbase+row)*CONVDIM + DI + NS + cg*8);
    *(uint4*)&sC[row*128 + ((cg ^ (row&15))<<3)] = u;
  }
  if (tid < 128) sDT[tid] = dtv[(rowbase+tid)*NH + h];
  __syncthreads();
  float inc = 0.f;
  if (tid < 128){
    inc = sDT[tid];
    #pragma unroll
    for (int off=1; off<64; off<<=1){
      float u = __shfl_up(inc, off);
      if (lane >= off) inc += u;
    }
    if (lane==63) sWT[wid] = inc;
  }
  __syncthreads();
  if (tid < 128){
    if (wid==1) inc += sWT[0];
    sAt[tid] = __expf(-eA*inc);
  }
  __syncthreads();

  int wrp = wid >> 1, wct = wid & 1;
  size_t sb = (((size_t)(b*NH+h))*NCH + c)*8192;
  f32x4 accP[2][4];
  #pragma unroll
  for (int i=0;i<2;i++)
    #pragma unroll
    for (int j=0;j<4;j++) accP[i][j] = (f32x4){0.f,0.f,0.f,0.f};
  #pragma unroll
  for (int ks=0; ks<4; ks++){
    bf16x8 af[2], bfv[4];
    #pragma unroll
    for (int mf=0;mf<2;mf++){
      int p = wrp*32 + mf*16 + r;
      af[mf] = *(const bf16x8*)(Sst + sb + (size_t)p*128 + ks*32 + q*8);
    }
    #pragma unroll
    for (int nf=0;nf<4;nf++){
      int t = wct*64 + nf*16 + r;
      bfv[nf] = *(const bf16x8*)&sC[t*128 + (((ks*4+q) ^ (t&15))<<3)];
    }
    #pragma unroll
    for (int mf=0;mf<2;mf++)
      #pragma unroll
      for (int nf=0;nf<4;nf++)
        accP[mf][nf] = __builtin_amdgcn_mfma_f32_16x16x32_bf16(af[mf], bfv[nf], accP[mf][nf], 0, 0, 0);
  }
  #pragma unroll
  for (int mf=0;mf<2;mf++){
    int pb = wrp*32 + mf*16 + q*4;
    #pragma unroll
    for (int nf=0;nf<4;nf++){
      int t = wct*64 + nf*16 + r;
      float at = sAt[t];
      bf16* yp = ys + (rowbase+t)*DI + h*HD + pb;
      uint2 old = *(uint2*)yp;
      float o0 = bf2f((bf16)(old.x & 0xffffu))  + at*accP[mf][nf][0];
      float o1 = bf2f((bf16)(old.x >> 16))      + at*accP[mf][nf][1];
      float o2 = bf2f((bf16)(old.y & 0xffffu))  + at*accP[mf][nf][2];
      float o3 = bf2f((bf16)(old.y >> 16))      + at*accP[mf][nf][3];
      *(uint2*)yp = make_uint2(pack2bf(o0,o1), pack2bf(o2,o3));
    }
  }
}

// ---------------- y = (ys + D*xh)*silu(z), RMSNorm*w, in place (bf16) ----------------
__global__ __launch_bounds__(256) void k_combine(bf16* __restrict__ ys, const bf16* __restrict__ xbc,
                         const bf16* __restrict__ z, const float* __restrict__ Dp,
                         const float* __restrict__ nw) {
  int bl = blockIdx.x;
  int tid = threadIdx.x;
  bf16* yrow = ys + (size_t)bl*DI;
  const bf16* xrow = xbc + (size_t)bl*CONVDIM;
  const bf16* zrow = z + (size_t)bl*DI;
  float v[2]; float ss = 0.f;
  #pragma unroll
  for (int i=0;i<2;i++) {
    int d = tid + i*256;
    float xh = bf2f(xrow[d]);
    float y = bf2f(yrow[d]) + Dp[d>>6]*xh;
    float zv = bf2f(zrow[d]);
    y *= zv / (1.f + expf(-zv));
    v[i] = y; ss += y*y;
  }
  #pragma unroll
  for (int off=1; off<64; off<<=1) ss += __shfl_xor(ss, off);
  __shared__ float sb[4];
  if ((tid&63)==0) sb[tid>>6]=ss;
  __syncthreads();
  float total = sb[0]+sb[1]+sb[2]+sb[3];
  float scale = rsqrtf(total * (1.f/512.f) + 1e-5f);
  #pragma unroll
  for (int i=0;i<2;i++) {
    int d = tid + i*256;
    yrow[d] = f2bf(v[i]*scale*nw[d]);
  }
}

extern "C" void kernel_launch(void* const* d_in, const int* in_sizes, int n_in,
                              void* d_out, int out_size, void* d_ws, size_t ws_size,
                              hipStream_t stream) {
  const float* x         = (const float*)d_in[0];
  const float* conv_w    = (const float*)d_in[1];
  const float* conv_b    = (const float*)d_in[2];
  const float* bn_gamma  = (const float*)d_in[3];
  const float* bn_beta   = (const float*)d_in[4];
  const float* patch_w   = (const float*)d_in[5];
  const float* patch_b   = (const float*)d_in[6];
  const float* in_proj_w = (const float*)d_in[7];
  const float* conv1d_w  = (const float*)d_in[8];
  const float* conv1d_b  = (const float*)d_in[9];
  const float* dt_bias   = (const float*)d_in[10];
  const float* A_log     = (const float*)d_in[11];
  const float* Dp        = (const float*)d_in[12];
  const float* norm_w    = (const float*)d_in[13];
  const float* out_proj_w= (const float*)d_in[14];
  const float* final_w   = (const float*)d_in[15];
  const float* final_b   = (const float*)d_in[16];
  float* out = (float*)d_out;

  char* Wb = (char*)d_ws;
  float* h_buf = (float*)(Wb + 0);
  bf16*  winb  = (bf16*)(Wb + 0);
  bf16*  woutb = (bf16*)(Wb + 0);
  bf16*  wfinb = (bf16*)(Wb + 262144);
  bf16*  xpost = (bf16*)(Wb + 0);
  float2* part = (float2*)(Wb + 50331648);
  bf16*  tok   = (bf16*)(Wb + 50331648);
  bf16*  zbuf  = (bf16*)(Wb + 67108864);
  bf16*  y2b   = (bf16*)(Wb + 67108864);
  bf16*  xpre  = (bf16*)(Wb + 100663296);
  bf16*  ysb   = (bf16*)(Wb + 100663296);
  bf16*  Sst   = (bf16*)(Wb + 134217728);
  float* dtv   = (float*)(Wb + 134217728 + 33554432);
  float* dAv   = dtv + 262144;
  float* stats = dAv + 262144;
  const size_t NEED = 134217728ull + 33554432 + 2097152 + 256;
  if (ws_size < NEED) {
    hipMemsetAsync(d_out, 0, (size_t)out_size*sizeof(float), stream);
    return;
  }

  k_conv1<<<dim3((B_*CMID*HMID*WMID)/256), dim3(256), 0, stream>>>(x, conv_w, conv_b, h_buf);
  k_bnstatsA<<<dim3(512), dim3(256), 0, stream>>>(h_buf, part);
  k_bnstatsB<<<dim3(1), dim3(64), 0, stream>>>(part, stats);
  k_patch<<<dim3(MTOK/8), dim3(256), 0, stream>>>(h_buf, patch_w, patch_b, stats, bn_gamma, bn_beta, tok);
  k_cvtw<<<dim3((NPADIN*DM)/256), dim3(256), 0, stream>>>(in_proj_w, winb, PROJ, 8, NPADIN*DM);
  k_mgemm<0><<<dim3(MTOK/256, NPADIN/128), dim3(512), 0, stream>>>(tok, winb, DM,
      zbuf, xpre, nullptr, nullptr, dt_bias, A_log, dtv, dAv, nullptr, nullptr);
  k_conv1d<<<dim3((MTOK/8*96)/256), dim3(256), 0, stream>>>(xpre, conv1d_w, conv1d_b, xpost);
  k_ssd1<<<dim3(B_*NH*NCH), dim3(512), 0, stream>>>(xpost, dtv, A_log, ysb, Sst);
  k_scan2<NCH,QCH><<<dim3(B_*NH*4), dim3(256), 0, stream>>>(Sst, dAv);
  k_ssd3<<<dim3(B_*NH*NCH), dim3(256), 0, stream>>>(xpost, dtv, A_log, Sst, ysb);
  k_combine<<<dim3(MTOK), dim3(256), 0, stream>>>(ysb, xpost, zbuf, Dp, norm_w);
  k_cvtw<<<dim3((DM*DI)/256), dim3(256), 0, stream>>>(out_proj_w, woutb, DM, 9, DM*DI);
  k_cvtw<<<dim3((128*DM)/256), dim3(256), 0, stream>>>(final_w, wfinb, 64, 8, 128*DM);
  k_mgemm<1><<<dim3(MTOK/256, DM/128), dim3(512), 0, stream>>>(ysb, woutb, DI,
      nullptr, nullptr, y2b, tok, nullptr, nullptr, nullptr, nullptr, nullptr, nullptr);
  k_mgemm<2><<<dim3(MTOK/256, 1), dim3(512), 0, stream>>>(y2b, wfinb, DM,
      nullptr, nullptr, nullptr, nullptr, nullptr, nullptr, nullptr, nullptr, out, final_b);
}

// Round 13
// 324.562 us; speedup vs baseline: 1.0380x; 1.0380x over previous
//
#include <hip/hip_runtime.h>
#include <math.h>

#define B_  8
#define CIN 3
#define HIN 256
#define WIN 256
#define CMID 16
#define HMID 128
#define WMID 128
#define DM 256
#define L_ 4096
#define DI 512
#define NH 8
#define HD 64
#define NS 128
#define KC 4
#define CONVDIM 768
#define PROJ 1288
#define NPADIN 1408
#define MTOK (B_*L_)
#define QCH 128          // chunk length (SSD)
#define NCH 32           // number of chunks

typedef unsigned short bf16;
typedef __attribute__((ext_vector_type(8))) short bf16x8;
typedef __attribute__((ext_vector_type(4))) float f32x4;

__device__ inline float bf2f(bf16 u) { return __uint_as_float(((unsigned int)u) << 16); }
__device__ inline bf16 f2bf(float f) {
  unsigned int x = __float_as_uint(f);
  return (bf16)((x + 0x7fffu + ((x >> 16) & 1u)) >> 16);
}
__device__ inline unsigned int pack2bf(float a, float b) {
  return (unsigned int)f2bf(a) | ((unsigned int)f2bf(b) << 16);
}

// ---------------- conv 3x3 stride 2 pad 1 ----------------
__global__ void k_conv1(const float* __restrict__ x, const float* __restrict__ w,
                        const float* __restrict__ bias, float* __restrict__ out) {
  int idx = blockIdx.x*256 + threadIdx.x;
  if (idx >= B_*CMID*HMID*WMID) return;
  int xo = idx & 127, yo = (idx>>7)&127, co = (idx>>14)&15, b = idx>>18;
  float acc = bias[co];
  const float* xb = x + (size_t)b*CIN*HIN*WIN;
  const float* wc = w + co*CIN*9;
  #pragma unroll
  for (int ci=0; ci<CIN; ci++)
    #pragma unroll
    for (int ky=0; ky<3; ky++) {
      int yi = 2*yo - 1 + ky;
      if (yi < 0 || yi >= HIN) continue;
      #pragma unroll
      for (int kx=0; kx<3; kx++) {
        int xi = 2*xo - 1 + kx;
        if (xi < 0 || xi >= WIN) continue;
        acc += xb[(ci*HIN + yi)*WIN + xi] * wc[(ci*3+ky)*3+kx];
      }
    }
  out[idx] = acc;
}

// ---------------- BN stats stage A ----------------
__global__ __launch_bounds__(256) void k_bnstatsA(const float* __restrict__ h, float2* __restrict__ part) {
  int blk = blockIdx.x;
  const float4* base = (const float4*)(h + ((size_t)(blk>>2))*16384 + (blk&3)*4096);
  int tid = threadIdx.x;
  float s=0.f, s2=0.f;
  #pragma unroll
  for (int i=0;i<4;i++){
    float4 v = base[i*256 + tid];
    s += v.x+v.y+v.z+v.w;
    s2 += v.x*v.x + v.y*v.y + v.z*v.z + v.w*v.w;
  }
  #pragma unroll
  for (int off=1; off<64; off<<=1) { s += __shfl_xor(s, off); s2 += __shfl_xor(s2, off); }
  __shared__ float sb[2][4];
  if ((tid&63)==0){ sb[0][tid>>6]=s; sb[1][tid>>6]=s2; }
  __syncthreads();
  if (tid==0) part[blk] = make_float2(sb[0][0]+sb[0][1]+sb[0][2]+sb[0][3],
                                      sb[1][0]+sb[1][1]+sb[1][2]+sb[1][3]);
}

// ---------------- BN stats stage B ----------------
__global__ void k_bnstatsB(const float2* __restrict__ part, float* __restrict__ stats) {
  int lane = threadIdx.x;
  int c = lane >> 2, j0 = lane & 3;
  float s=0.f, s2=0.f;
  #pragma unroll
  for (int j=j0; j<32; j+=4){
    int b = j >> 2, chunk = j & 3;
    float2 p = part[(b*16+c)*4 + chunk];
    s += p.x; s2 += p.y;
  }
  s += __shfl_xor(s,1); s2 += __shfl_xor(s2,1);
  s += __shfl_xor(s,2); s2 += __shfl_xor(s2,2);
  if (j0==0){
    const float inv = 1.f/131072.f;
    float mean = s*inv;
    float var  = s2*inv - mean*mean;
    stats[c]      = mean;
    stats[16 + c] = rsqrtf(var + 1e-5f);
  }
}

// ---------------- patch conv 2x2 s2 (+fused BN+GELU) + bias + sincos -> tok ----------------
__global__ __launch_bounds__(256) void k_patch(const float* __restrict__ h, const float* __restrict__ pw,
                       const float* __restrict__ pb, const float* __restrict__ stats,
                       const float* __restrict__ gamma, const float* __restrict__ beta,
                       bf16* __restrict__ tok) {
  int grp = blockIdx.x;
  int b = grp >> 9, g8 = grp & 511;
  int g0 = g8 << 3;
  int gy = g0 >> 6, gx0 = g0 & 63;
  __shared__ float sh[8][64];
  int tid = threadIdx.x;
  {
    int tk = tid >> 5, jj = (tid & 31)*2;
    int ci = jj >> 2, p = (jj >> 1) & 1;
    const float* src = &h[((size_t)(b*CMID+ci)*HMID + 2*gy+p)*WMID + 2*(gx0+tk)];
    float2 xv = *(const float2*)src;
    float mean = stats[ci], rstd = stats[16+ci];
    float sc = rstd*gamma[ci], be = beta[ci] - mean*sc;
    float v0 = xv.x*sc + be;
    float v1 = xv.y*sc + be;
    v0 = 0.5f*v0*(1.f + erff(v0*0.70710678118654752f));
    v1 = 0.5f*v1*(1.f + erff(v1*0.70710678118654752f));
    sh[tk][jj] = v0; sh[tk][jj+1] = v1;
  }
  __syncthreads();
  int d = tid;
  float wr[64];
  #pragma unroll
  for (int i4=0;i4<16;i4++) *(float4*)&wr[i4*4] = *(const float4*)&pw[d*64 + i4*4];
  float bias = pb[d];
  int i = d & 63;
  float omega = expf(-(float)i * (9.210340371976184f/64.f));
  #pragma unroll
  for (int tk=0;tk<8;tk++){
    float acc = bias;
    #pragma unroll
    for (int j=0;j<64;j++) acc = fmaf(sh[tk][j], wr[j], acc);
    float gv = (d < 128) ? (float)(gx0+tk) : (float)gy;
    float ph = gv * omega;
    float pos = (d & 64) ? __cosf(ph) : __sinf(ph);
    tok[((size_t)((b<<12) + g0 + tk))*DM + d] = f2bf(acc + pos);
  }
}

// ---------------- weight f32 -> bf16 (with zero-padding to Npad rows) ----------------
__global__ void k_cvtw(const float* __restrict__ src, bf16* __restrict__ dst,
                       int N, int kshift, int total) {
  int idx = blockIdx.x*256 + threadIdx.x;
  if (idx >= total) return;
  int n = idx >> kshift;
  dst[idx] = (n < N) ? f2bf(src[idx]) : (bf16)0;
}

// ---------------- MFMA bf16 GEMM, 256x128 tile, 512 thr, swapped, LDS-coalesced epilogue ----------------
template<int EPI>
__global__ __launch_bounds__(512) void k_mgemm(
    const bf16* __restrict__ A, const bf16* __restrict__ Bw, int K,
    bf16* __restrict__ o_z, bf16* __restrict__ o_x,
    bf16* __restrict__ o_y, const bf16* __restrict__ res,
    const float* __restrict__ dt_bias, const float* __restrict__ A_log,
    float* __restrict__ dtv, float* __restrict__ dAv,
    float* __restrict__ o_f, const float* __restrict__ fbias) {
  __shared__ __align__(16) char smem[49152];
  bf16* sA = (bf16*)smem;                 // 2 bufs x 256x32 = 32KB
  bf16* sB = (bf16*)(smem + 32768);       // 2 bufs x 128x32 = 16KB
  bf16* sT = (bf16*)smem;                 // 256x72 bf16 = 36KB, reused post-loop
  int tid = threadIdx.x;
  int lane = tid & 63, wid = tid >> 6;     // 8 waves
  int wr = wid >> 1, wc = wid & 1;         // wr: m tile (4x64), wc: n half (2x64)
  int m0 = blockIdx.x*256, n0 = blockIdx.y*128;
  int nk = K >> 5;

  f32x4 acc[4][4];
  #pragma unroll
  for (int i=0;i<4;i++)
    #pragma unroll
    for (int j=0;j<4;j++)
      acc[i][j] = (f32x4){0.f,0.f,0.f,0.f};

  auto stage = [&](int buf, int ks){
    int kk = ks << 5;
    #pragma unroll
    for (int i=0;i<2;i++){
      int j = i*512 + tid;
      int row = j >> 2, cc = j & 3;
      int kg = cc ^ (row & 3);
      unsigned ldsoff = (unsigned)(buf*16384 + (i*512 + wid*64) * 16);
      __builtin_amdgcn_global_load_lds(
        (const __attribute__((address_space(1))) void*)(A + (size_t)(m0+row)*K + kk + kg*8),
        (__attribute__((address_space(3))) void*)((char*)sA + ldsoff), 16, 0, 0);
    }
    {
      int row = tid >> 2, cc = tid & 3;
      int kg = cc ^ (row & 3);
      unsigned ldsoff = (unsigned)(buf*8192 + (wid*64) * 16);
      __builtin_amdgcn_global_load_lds(
        (const __attribute__((address_space(1))) void*)(Bw + (size_t)(n0+row)*K + kk + kg*8),
        (__attribute__((address_space(3))) void*)((char*)sB + ldsoff), 16, 0, 0);
    }
  };

  int r = lane & 15, q = lane >> 4;
  int kgo = (q ^ (r & 3)) << 3;

  stage(0, 0);
  for (int ks=0; ks<nk; ++ks){
    int cur = ks & 1;
    __syncthreads();
    if (ks+1 < nk) stage(cur^1, ks+1);
    bf16x8 af[4], bfv[4];
    #pragma unroll
    for (int a=0;a<4;a++){
      int rown = wc*64 + a*16 + r;
      af[a] = *(const bf16x8*)&sB[cur*4096 + rown*32 + kgo];
    }
    #pragma unroll
    for (int bfr=0;bfr<4;bfr++){
      int rowm = wr*64 + bfr*16 + r;
      bfv[bfr] = *(const bf16x8*)&sA[cur*8192 + rowm*32 + kgo];
    }
    #pragma unroll
    for (int a=0;a<4;a++)
      #pragma unroll
      for (int bfr=0;bfr<4;bfr++)
        acc[a][bfr] = __builtin_amdgcn_mfma_f32_16x16x32_bf16(af[a], bfv[bfr], acc[a][bfr], 0, 0, 0);
  }

  // ---- dt tile (EPI0, n0 == 1280): scalar routing only, skip transpose ----
  if (EPI == 0 && n0 >= DI + CONVDIM) {
    #pragma unroll
    for (int a=0;a<4;a++){
      int n4 = n0 + wc*64 + a*16 + q*4;
      if (n4 >= PROJ) continue;
      #pragma unroll
      for (int bfr=0;bfr<4;bfr++){
        int m = m0 + wr*64 + bfr*16 + r;
        f32x4 v = acc[a][bfr];
        #pragma unroll
        for (int rr=0;rr<4;rr++){
          int hh = n4 + rr - (DI + CONVDIM);
          if (hh < NH){
            float xv = v[rr] + dt_bias[hh];
            float dt = (xv > 20.f) ? xv : log1pf(expf(xv));
            dtv[(size_t)m*NH + hh] = dt;
            dAv[(size_t)m*NH + hh] = expf(-expf(A_log[hh]) * dt);
          }
        }
      }
    }
    return;
  }

  // ---- transpose-through-LDS coalesced epilogue (EPI0 z/x tiles) ----
  #pragma unroll
  for (int h2=0; h2<2; ++h2){
    __syncthreads();
    if (wc == h2){
      #pragma unroll
      for (int a=0;a<4;a++){
        int nl = a*16 + q*4;
        #pragma unroll
        for (int bfr=0;bfr<4;bfr++){
          int ml = wr*64 + bfr*16 + r;
          f32x4 v = acc[a][bfr];
          *(uint2*)&sT[ml*72 + nl] = make_uint2(pack2bf(v[0],v[1]), pack2bf(v[2],v[3]));
        }
      }
    }
    __syncthreads();
    int ml = tid >> 1, ch = tid & 1;
    int m = m0 + ml;
    int ncol = n0 + h2*64 + ch*32;
    const bf16* src = &sT[ml*72 + ch*32];
    bf16* dst = (n0 < DI) ? (o_z + (size_t)m*DI + ncol)
                          : (o_x + (size_t)m*CONVDIM + (ncol - DI));
    #pragma unroll
    for (int i4=0;i4<4;i4++)
      *(uint4*)(dst + i4*8) = *(const uint4*)(src + i4*8);
  }
}

// ---------------- FUSED out_proj + residual + final GEMM + pixel-shuffle ----------------
// Tile: M=128 (tokens), N=256 (=DM full), K=512. 8 waves = 2m x 4n; acc[n-frag][m-frag].
// After main loop: y2 = acc + tok residual. Second GEMM over k-chunks of 64 (one per wc):
// chunk waves write bf16 y2 frags into swizzled sY[128][64]; all waves accumulate
// out[o,m] += mfma(wfin o-rows (global L2), y2 m-rows (sY)). Scatter with pixel shuffle.
__global__ __launch_bounds__(512) void k_mgemm12(
    const bf16* __restrict__ A, const bf16* __restrict__ Bw,
    const bf16* __restrict__ res, const bf16* __restrict__ wfin,
    const float* __restrict__ fbias, float* __restrict__ o_f) {
  __shared__ __align__(16) char smem[49152];
  bf16* sA = (bf16*)smem;                 // 2 bufs x 128x32 = 16KB
  bf16* sB = (bf16*)(smem + 16384);       // 2 bufs x 256x32 = 32KB
  bf16* sY = (bf16*)smem;                 // 128x64 bf16 = 16KB, reused post-loop
  int tid = threadIdx.x;
  int lane = tid & 63, wid = tid >> 6;     // 8 waves
  int wr = wid >> 2, wc = wid & 3;         // wr: m tile (2x64), wc: n tile (4x64)
  int m0 = blockIdx.x*128;
  const int K = DI;                        // 512
  int nk = K >> 5;                         // 16

  f32x4 acc[4][4];
  #pragma unroll
  for (int i=0;i<4;i++)
    #pragma unroll
    for (int j=0;j<4;j++)
      acc[i][j] = (f32x4){0.f,0.f,0.f,0.f};

  auto stage = [&](int buf, int ks){
    int kk = ks << 5;
    {
      int row = tid >> 2, cc = tid & 3;    // 128 rows x 4 chunks
      int kg = cc ^ (row & 3);
      unsigned ldsoff = (unsigned)(buf*8192 + (wid*64) * 16);
      __builtin_amdgcn_global_load_lds(
        (const __attribute__((address_space(1))) void*)(A + (size_t)(m0+row)*K + kk + kg*8),
        (__attribute__((address_space(3))) void*)((char*)sA + ldsoff), 16, 0, 0);
    }
    #pragma unroll
    for (int i=0;i<2;i++){
      int j = i*512 + tid;                 // 256 rows x 4 chunks
      int row = j >> 2, cc = j & 3;
      int kg = cc ^ (row & 3);
      unsigned ldsoff = (unsigned)(buf*16384 + (i*512 + wid*64) * 16);
      __builtin_amdgcn_global_load_lds(
        (const __attribute__((address_space(1))) void*)(Bw + (size_t)row*K + kk + kg*8),
        (__attribute__((address_space(3))) void*)((char*)sB + ldsoff), 16, 0, 0);
    }
  };

  int r = lane & 15, q = lane >> 4;
  int kgo = (q ^ (r & 3)) << 3;

  stage(0, 0);
  for (int ks=0; ks<nk; ++ks){
    int cur = ks & 1;
    __syncthreads();
    if (ks+1 < nk) stage(cur^1, ks+1);
    bf16x8 af[4], bfv[4];
    #pragma unroll
    for (int a=0;a<4;a++){
      int rown = wc*64 + a*16 + r;
      af[a] = *(const bf16x8*)&sB[cur*8192 + rown*32 + kgo];
    }
    #pragma unroll
    for (int mf=0;mf<4;mf++){
      int rowm = wr*64 + mf*16 + r;
      bfv[mf] = *(const bf16x8*)&sA[cur*4096 + rowm*32 + kgo];
    }
    #pragma unroll
    for (int a=0;a<4;a++)
      #pragma unroll
      for (int mf=0;mf<4;mf++)
        acc[a][mf] = __builtin_amdgcn_mfma_f32_16x16x32_bf16(af[a], bfv[mf], acc[a][mf], 0, 0, 0);
  }

  // second GEMM: out[128 m][64 o], K2 = 256 (n-dim), chunks of 64
  f32x4 acc2[4];
  #pragma unroll
  for (int i=0;i<4;i++) acc2[i] = (f32x4){0.f,0.f,0.f,0.f};
  int orow = wc*16 + r;                    // o index for wfin fragment rows

  #pragma unroll
  for (int j=0;j<4;j++){
    __syncthreads();                       // protects sY (and sA on j==0)
    if (wc == j){
      // write y2 = acc + res into sY [m_local][k_local], chunk-XOR swizzle
      #pragma unroll
      for (int a=0;a<4;a++){
        int kl = a*16 + q*4;
        int chunk = kl >> 3, sub = (q & 1)*4;
        #pragma unroll
        for (int mf=0;mf<4;mf++){
          int ml = wr*64 + mf*16 + r;
          int m = m0 + ml;
          int n4 = wc*64 + kl;
          uint2 rv = *(const uint2*)(res + (size_t)m*DM + n4);
          f32x4 v = acc[a][mf];
          float y0 = v[0] + bf2f((bf16)(rv.x & 0xffffu));
          float y1 = v[1] + bf2f((bf16)(rv.x >> 16));
          float y2 = v[2] + bf2f((bf16)(rv.y & 0xffffu));
          float y3 = v[3] + bf2f((bf16)(rv.y >> 16));
          *(uint2*)&sY[ml*64 + ((chunk ^ (ml&7))<<3) + sub] =
              make_uint2(pack2bf(y0,y1), pack2bf(y2,y3));
        }
      }
    }
    __syncthreads();
    #pragma unroll
    for (int kstep=0;kstep<2;kstep++){
      bf16x8 af2 = *(const bf16x8*)(wfin + (size_t)orow*DM + j*64 + kstep*32 + q*8);
      #pragma unroll
      for (int mf=0;mf<4;mf++){
        int ml = wr*64 + mf*16 + r;
        int cg = kstep*4 + q;
        bf16x8 bv = *(const bf16x8*)&sY[ml*64 + ((cg ^ (ml&7))<<3)];
        acc2[mf] = __builtin_amdgcn_mfma_f32_16x16x32_bf16(af2, bv, acc2[mf], 0, 0, 0);
      }
    }
  }

  // scatter: rows of acc2 = o quad (wc*16 + q*4 + rr), col = m
  #pragma unroll
  for (int mf=0;mf<4;mf++){
    int m = m0 + wr*64 + mf*16 + r;
    int b = m >> 12, g = m & 4095;
    int gy = g >> 6, gx = g & 63;
    f32x4 v = acc2[mf];
    #pragma unroll
    for (int rr=0;rr<4;rr++){
      int o = wc*16 + q*4 + rr;
      float vv = v[rr] + fbias[o];
      int p = o >> 5, qq = (o>>4)&1, cc2 = o & 15;
      o_f[(((size_t)(b*CMID+cc2))*HMID + 2*gy+p)*WMID + (2*gx+qq)] = vv;
    }
  }
}

// ---------------- causal depthwise conv1d (KC=4) + bias + silu ----------------
__global__ __launch_bounds__(256) void k_conv1d(const bf16* __restrict__ xpre, const float* __restrict__ cw,
                         const float* __restrict__ cb, bf16* __restrict__ xbc) {
  int idx = blockIdx.x*256 + threadIdx.x;
  int gch = idx % 96;
  int tb  = idx / 96;
  int ch0 = gch*8;
  int bl0 = tb*8;
  int l0 = bl0 & (L_-1);
  float wv[32];
  #pragma unroll
  for (int i=0;i<8;i++) *(float4*)&wv[i*4] = *(const float4*)&cw[ch0*KC + i*4];
  float bs[8];
  *(float4*)&bs[0] = *(const float4*)&cb[ch0];
  *(float4*)&bs[4] = *(const float4*)&cb[ch0+4];
  uint4 rows[11];
  #pragma unroll
  for (int j=0;j<11;j++){
    int lk = l0 - 3 + j;
    if (lk < 0) rows[j] = make_uint4(0u,0u,0u,0u);
    else rows[j] = *(const uint4*)(xpre + ((size_t)bl0 - 3 + j)*CONVDIM + ch0);
  }
  #pragma unroll
  for (int t=0;t<8;t++){
    float acc[8];
    #pragma unroll
    for (int i=0;i<8;i++) acc[i] = bs[i];
    #pragma unroll
    for (int k=0;k<KC;k++){
      uint4 u = rows[t+k];
      unsigned uu[4]={u.x,u.y,u.z,u.w};
      #pragma unroll
      for (int c2=0;c2<4;c2++){
        float lo = __uint_as_float(uu[c2]<<16);
        float hi = __uint_as_float(uu[c2]&0xffff0000u);
        acc[c2*2]   = fmaf(wv[(c2*2)*4 + k],   lo, acc[c2*2]);
        acc[c2*2+1] = fmaf(wv[(c2*2+1)*4 + k], hi, acc[c2*2+1]);
      }
    }
    unsigned ou[4];
    #pragma unroll
    for (int c2=0;c2<4;c2++){
      float v0 = acc[c2*2], v1 = acc[c2*2+1];
      v0 = v0 / (1.f + __expf(-v0));
      v1 = v1 / (1.f + __expf(-v1));
      ou[c2] = pack2bf(v0, v1);
    }
    *(uint4*)(xbc + (size_t)(bl0+t)*CONVDIM + ch0) = make_uint4(ou[0],ou[1],ou[2],ou[3]);
  }
}

// ================= SSD pass 1: 80KB LDS (2 blocks/CU), in-place BT, late DX =================
__global__ __launch_bounds__(512) void k_ssd1(const bf16* __restrict__ xbc,
    const float* __restrict__ dtv, const float* __restrict__ A_log,
    bf16* __restrict__ ys, bf16* __restrict__ Sst) {
  int blk = blockIdx.x;
  int c = blk & (NCH-1), h = (blk>>5)&7, b = blk>>8;
  int tid = threadIdx.x;
  int lane = tid & 63, wid = tid >> 6;     // 8 waves
  int r = lane & 15, q = lane >> 4;
  size_t rowbase = (size_t)b*L_ + (size_t)c*QCH;
  float eA = __expf(A_log[h]);

  __shared__ __align__(16) char smem[81920];
  bf16* sB  = (bf16*)smem;
  bf16* sC  = (bf16*)(smem + 32768);
  bf16* sDX = (bf16*)(smem + 65536);
  float* fDT = (float*)(smem + 65536);
  float* fL  = fDT + 128;
  float* fWS = fL + 128;
  float* fWT = fWS + 128;

  #pragma unroll
  for (int i=0;i<8;i++){
    int id = i*512 + tid;
    int row = id >> 5, cg = id & 31;
    uint4 u = *(const uint4*)(xbc + (rowbase+row)*CONVDIM + DI + cg*8);
    if (cg < 16) *(uint4*)&sB[row*128 + ((cg ^ (row&15))<<3)] = u;
    else { int cg2 = cg-16; *(uint4*)&sC[row*128 + ((cg2 ^ (row&15))<<3)] = u; }
  }
  if (tid < 128) fDT[tid] = dtv[(rowbase+tid)*NH + h];
  __syncthreads();

  float inc = 0.f;
  if (tid < 128){
    inc = fDT[tid];
    #pragma unroll
    for (int off=1; off<64; off<<=1){
      float u = __shfl_up(inc, off);
      if (lane >= off) inc += u;
    }
    if (lane==63) fWT[wid] = inc;
  }
  __syncthreads();
  if (tid < 128){
    if (wid==1) inc += fWT[0];
    fL[tid] = inc;
  }

  int wr = wid >> 1, wc = wid & 1;
  f32x4 accG[2][4];
  #pragma unroll
  for (int i=0;i<2;i++)
    #pragma unroll
    for (int j=0;j<4;j++) accG[i][j] = (f32x4){0.f,0.f,0.f,0.f};
  #pragma unroll
  for (int ks=0; ks<4; ks++){
    bf16x8 af[2], bfv[4];
    #pragma unroll
    for (int mf=0;mf<2;mf++){
      int s = wr*32 + mf*16 + r;
      af[mf] = *(const bf16x8*)&sB[s*128 + (((ks*4+q) ^ (s&15))<<3)];
    }
    #pragma unroll
    for (int nf=0;nf<4;nf++){
      int t = wc*64 + nf*16 + r;
      bfv[nf] = *(const bf16x8*)&sC[t*128 + (((ks*4+q) ^ (t&15))<<3)];
    }
    #pragma unroll
    for (int mf=0;mf<2;mf++)
      #pragma unroll
      for (int nf=0;nf<4;nf++)
        accG[mf][nf] = __builtin_amdgcn_mfma_f32_16x16x32_bf16(af[mf], bfv[nf], accG[mf][nf], 0, 0, 0);
  }
  __syncthreads();

  bf16* sW = sC;
  #pragma unroll
  for (int mf=0;mf<2;mf++){
    int sb4 = wr*32 + mf*16 + q*4;
    int cb4 = sb4 >> 3, se4 = sb4 & 7;
    #pragma unroll
    for (int nf=0;nf<4;nf++){
      int t = wc*64 + nf*16 + r;
      float Lt = fL[t];
      float w[4];
      #pragma unroll
      for (int rr=0;rr<4;rr++){
        int s = sb4 + rr;
        float v = 0.f;
        if (s <= t) v = accG[mf][nf][rr] * fDT[s] * __expf(-eA*(Lt - fL[s]));
        w[rr] = v;
      }
      *(uint2*)&sW[t*128 + ((cb4 ^ (t&15))<<3) + se4] =
          make_uint2(pack2bf(w[0],w[1]), pack2bf(w[2],w[3]));
    }
  }
  if (tid < 128) fWS[tid] = fDT[tid]*__expf(-eA*(fL[127]-fL[tid]));
  __syncthreads();

  int nT = tid >> 2, sg = tid & 3;
  unsigned short vals[32];
  #pragma unroll
  for (int i8=0;i8<4;i8++){
    #pragma unroll
    for (int j=0;j<8;j++){
      int s = sg*32 + i8*8 + j;
      float bv = bf2f(sB[s*128 + (((nT>>3) ^ (s&15))<<3) + (nT&7)]);
      vals[i8*8+j] = f2bf(bv * fWS[s]);
    }
  }
  __syncthreads();

  #pragma unroll
  for (int i8=0;i8<4;i8++){
    int s8 = sg*4 + i8;
    *(uint4*)&sB[nT*128 + ((s8 ^ (nT&15))<<3)] = *(const uint4*)&vals[i8*8];
  }
  {
    int s0 = (tid >> 3)*2;
    int p0 = (tid & 7)*8;
    const bf16* x0 = xbc + (rowbase+s0)*CONVDIM + h*HD + p0;
    uint4 u0 = *(const uint4*)x0;
    uint4 u1 = *(const uint4*)(x0 + CONVDIM);
    unsigned a0[4]={u0.x,u0.y,u0.z,u0.w}, a1[4]={u1.x,u1.y,u1.z,u1.w};
    int cb2 = s0 >> 3, se = s0 & 7;
    #pragma unroll
    for (int jp=0;jp<4;jp++){
      unsigned w0=a0[jp], w1=a1[jp];
      unsigned lo = (w0 & 0xffffu) | (w1 << 16);
      unsigned hi = (w0 >> 16) | (w1 & 0xffff0000u);
      int pA = p0 + jp*2, pB = pA+1;
      *(unsigned*)&sDX[pA*128 + ((cb2 ^ (pA&15))<<3) + se] = lo;
      *(unsigned*)&sDX[pB*128 + ((cb2 ^ (pB&15))<<3) + se] = hi;
    }
  }
  __syncthreads();

  {
    int wrp = wid >> 2, wct = wid & 3;
    f32x4 acc2[2][2];
    #pragma unroll
    for (int i=0;i<2;i++){ acc2[i][0]=(f32x4){0.f,0.f,0.f,0.f}; acc2[i][1]=(f32x4){0.f,0.f,0.f,0.f}; }
    #pragma unroll
    for (int ks=0; ks<4; ks++){
      bf16x8 af[2], bfv[2];
      #pragma unroll
      for (int mf=0;mf<2;mf++){
        int p = wrp*32 + mf*16 + r;
        af[mf] = *(const bf16x8*)&sDX[p*128 + (((ks*4+q) ^ (p&15))<<3)];
      }
      #pragma unroll
      for (int nf=0;nf<2;nf++){
        int t = wct*32 + nf*16 + r;
        bfv[nf] = *(const bf16x8*)&sW[t*128 + (((ks*4+q) ^ (t&15))<<3)];
      }
      #pragma unroll
      for (int mf=0;mf<2;mf++)
        #pragma unroll
        for (int nf=0;nf<2;nf++)
          acc2[mf][nf] = __builtin_amdgcn_mfma_f32_16x16x32_bf16(af[mf], bfv[nf], acc2[mf][nf], 0, 0, 0);
    }
    #pragma unroll
    for (int mf=0;mf<2;mf++){
      int pb = wrp*32 + mf*16 + q*4;
      #pragma unroll
      for (int nf=0;nf<2;nf++){
        int t = wct*32 + nf*16 + r;
        f32x4 v = acc2[mf][nf];
        *(uint2*)(ys + (rowbase+t)*DI + h*HD + pb) =
            make_uint2(pack2bf(v[0],v[1]), pack2bf(v[2],v[3]));
      }
    }
  }
  {
    int wrn = wid >> 1, wcp = wid & 1;
    f32x4 acc3[2][2];
    #pragma unroll
    for (int i=0;i<2;i++){ acc3[i][0]=(f32x4){0.f,0.f,0.f,0.f}; acc3[i][1]=(f32x4){0.f,0.f,0.f,0.f}; }
    #pragma unroll
    for (int ks=0; ks<4; ks++){
      bf16x8 af[2], bfv[2];
      #pragma unroll
      for (int mf=0;mf<2;mf++){
        int n = wrn*32 + mf*16 + r;
        af[mf] = *(const bf16x8*)&sB[n*128 + (((ks*4+q) ^ (n&15))<<3)];
      }
      #pragma unroll
      for (int nf=0;nf<2;nf++){
        int p = wcp*32 + nf*16 + r;
        bfv[nf] = *(const bf16x8*)&sDX[p*128 + (((ks*4+q) ^ (p&15))<<3)];
      }
      #pragma unroll
      for (int mf=0;mf<2;mf++)
        #pragma unroll
        for (int nf=0;nf<2;nf++)
          acc3[mf][nf] = __builtin_amdgcn_mfma_f32_16x16x32_bf16(af[mf], bfv[nf], acc3[mf][nf], 0, 0, 0);
    }
    size_t sb = (((size_t)(b*NH+h))*NCH + c)*8192;
    #pragma unroll
    for (int mf=0;mf<2;mf++){
      int nb = wrn*32 + mf*16 + q*4;
      #pragma unroll
      for (int nf=0;nf<2;nf++){
        int p = wcp*32 + nf*16 + r;
        f32x4 v = acc3[mf][nf];
        *(uint2*)(Sst + sb + (size_t)p*128 + nb) =
            make_uint2(pack2bf(v[0],v[1]), pack2bf(v[2],v[3]));
      }
    }
  }
}

// ---------------- pass 2: prefix-combine chunk states ----------------
template<int NCHT, int QCHT>
__global__ __launch_bounds__(256) void k_scan2(bf16* __restrict__ Sst, const float* __restrict__ dAv) {
  constexpr int SEG = QCHT/16;
  int blk = blockIdx.x;
  int bh = blk>>2, q = blk&3;
  int b = bh>>3, h = bh&7;
  int tid = threadIdx.x;
  __shared__ float sP[NCHT];
  {
    int c = tid / SEG, seg = tid & (SEG-1);
    float prod = 1.f;
    size_t base = ((size_t)b*L_ + c*QCHT + seg*16)*NH + h;
    #pragma unroll
    for (int k=0;k<16;k++) prod *= dAv[base + (size_t)k*NH];
    #pragma unroll
    for (int off=1; off<SEG; off<<=1) prod *= __shfl_xor(prod, off);
    if (seg==0) sP[c] = prod;
  }
  __syncthreads();
  int e0 = q*2048 + tid*8;
  float acc[8];
  #pragma unroll
  for (int j=0;j<8;j++) acc[j]=0.f;
  size_t sbase = (size_t)bh*NCHT*8192 + e0;
  for (int c=0;c<NCHT;c++){
    bf16* ptr = Sst + sbase + (size_t)c*8192;
    uint4 u = *(const uint4*)ptr;
    unsigned int uu[4] = {u.x,u.y,u.z,u.w};
    float tv[8];
    #pragma unroll
    for (int k=0;k<4;k++){
      tv[2*k]   = __uint_as_float(uu[k]<<16);
      tv[2*k+1] = __uint_as_float(uu[k]&0xffff0000u);
    }
    uint4 o;
    o.x = pack2bf(acc[0],acc[1]); o.y = pack2bf(acc[2],acc[3]);
    o.z = pack2bf(acc[4],acc[5]); o.w = pack2bf(acc[6],acc[7]);
    asm volatile("s_waitcnt vmcnt(0)" ::: "memory");
    *(uint4*)ptr = o;
    float P = sP[c];
    #pragma unroll
    for (int j=0;j<8;j++) acc[j] = tv[j] + P*acc[j];
  }
}

// ================= SSD pass 3: Y += exp(-eA*L_t) * (C x I_c), swapped (b64 RMW) =================
__global__ __launch_bounds__(256) void k_ssd3(const bf16* __restrict__ xbc,
    const float* __restrict__ dtv, const float* __restrict__ A_log,
    const bf16* __restrict__ Sst, bf16* __restrict__ ys) {
  int blk = blockIdx.x;
  int c = blk & (NCH-1), h = (blk>>5)&7, b = blk>>8;
  int tid = threadIdx.x;
  int lane = tid & 63, wid = tid >> 6;
  int r = lane & 15, q = lane >> 4;
  size_t rowbase = (size_t)b*L_ + (size_t)c*QCH;
  float eA = __expf(A_log[h]);

  __shared__ __align__(16) bf16 sC[128*128];
  __shared__ float sDT[128];
  __shared__ float sAt[128];
  __shared__ float sWT[2];

  #pragma unroll
  for (int i=0;i<8;i++){
    int id = i*256 + tid;
    int row = id >> 4, cg = id & 15;
    uint4 u = *(const uint4*)(xbc + (rowbase+row)*CONVDIM + DI + NS + cg*8);
    *(uint4*)&sC[row*128 + ((cg ^ (row&15))<<3)] = u;
  }
  if (tid < 128) sDT[tid] = dtv[(rowbase+tid)*NH + h];
  __syncthreads();
  float inc = 0.f;
  if (tid < 128){
    inc = sDT[tid];
    #pragma unroll
    for (int off=1; off<64; off<<=1){
      float u = __shfl_up(inc, off);
      if (lane >= off) inc += u;
    }
    if (lane==63) sWT[wid] = inc;
  }
  __syncthreads();
  if (tid < 128){
    if (wid==1) inc += sWT[0];
    sAt[tid] = __expf(-eA*inc);
  }
  __syncthreads();

  int wrp = wid >> 1, wct = wid & 1;
  size_t sb = (((size_t)(b*NH+h))*NCH + c)*8192;
  f32x4 accP[2][4];
  #pragma unroll
  for (int i=0;i<2;i++)
    #pragma unroll
    for (int j=0;j<4;j++) accP[i][j] = (f32x4){0.f,0.f,0.f,0.f};
  #pragma unroll
  for (int ks=0; ks<4; ks++){
    bf16x8 af[2], bfv[4];
    #pragma unroll
    for (int mf=0;mf<2;mf++){
      int p = wrp*32 + mf*16 + r;
      af[mf] = *(const bf16x8*)(Sst + sb + (size_t)p*128 + ks*32 + q*8);
    }
    #pragma unroll
    for (int nf=0;nf<4;nf++){
      int t = wct*64 + nf*16 + r;
      bfv[nf] = *(const bf16x8*)&sC[t*128 + (((ks*4+q) ^ (t&15))<<3)];
    }
    #pragma unroll
    for (int mf=0;mf<2;mf++)
      #pragma unroll
      for (int nf=0;nf<4;nf++)
        accP[mf][nf] = __builtin_amdgcn_mfma_f32_16x16x32_bf16(af[mf], bfv[nf], accP[mf][nf], 0, 0, 0);
  }
  #pragma unroll
  for (int mf=0;mf<2;mf++){
    int pb = wrp*32 + mf*16 + q*4;
    #pragma unroll
    for (int nf=0;nf<4;nf++){
      int t = wct*64 + nf*16 + r;
      float at = sAt[t];
      bf16* yp = ys + (rowbase+t)*DI + h*HD + pb;
      uint2 old = *(uint2*)yp;
      float o0 = bf2f((bf16)(old.x & 0xffffu))  + at*accP[mf][nf][0];
      float o1 = bf2f((bf16)(old.x >> 16))      + at*accP[mf][nf][1];
      float o2 = bf2f((bf16)(old.y & 0xffffu))  + at*accP[mf][nf][2];
      float o3 = bf2f((bf16)(old.y >> 16))      + at*accP[mf][nf][3];
      *(uint2*)yp = make_uint2(pack2bf(o0,o1), pack2bf(o2,o3));
    }
  }
}

// ---------------- y = (ys + D*xh)*silu(z), RMSNorm*w, in place (bf16) ----------------
__global__ __launch_bounds__(256) void k_combine(bf16* __restrict__ ys, const bf16* __restrict__ xbc,
                         const bf16* __restrict__ z, const float* __restrict__ Dp,
                         const float* __restrict__ nw) {
  int bl = blockIdx.x;
  int tid = threadIdx.x;
  bf16* yrow = ys + (size_t)bl*DI;
  const bf16* xrow = xbc + (size_t)bl*CONVDIM;
  const bf16* zrow = z + (size_t)bl*DI;
  float v[2]; float ss = 0.f;
  #pragma unroll
  for (int i=0;i<2;i++) {
    int d = tid + i*256;
    float xh = bf2f(xrow[d]);
    float y = bf2f(yrow[d]) + Dp[d>>6]*xh;
    float zv = bf2f(zrow[d]);
    y *= zv / (1.f + expf(-zv));
    v[i] = y; ss += y*y;
  }
  #pragma unroll
  for (int off=1; off<64; off<<=1) ss += __shfl_xor(ss, off);
  __shared__ float sb[4];
  if ((tid&63)==0) sb[tid>>6]=ss;
  __syncthreads();
  float total = sb[0]+sb[1]+sb[2]+sb[3];
  float scale = rsqrtf(total * (1.f/512.f) + 1e-5f);
  #pragma unroll
  for (int i=0;i<2;i++) {
    int d = tid + i*256;
    yrow[d] = f2bf(v[i]*scale*nw[d]);
  }
}

extern "C" void kernel_launch(void* const* d_in, const int* in_sizes, int n_in,
                              void* d_out, int out_size, void* d_ws, size_t ws_size,
                              hipStream_t stream) {
  const float* x         = (const float*)d_in[0];
  const float* conv_w    = (const float*)d_in[1];
  const float* conv_b    = (const float*)d_in[2];
  const float* bn_gamma  = (const float*)d_in[3];
  const float* bn_beta   = (const float*)d_in[4];
  const float* patch_w   = (const float*)d_in[5];
  const float* patch_b   = (const float*)d_in[6];
  const float* in_proj_w = (const float*)d_in[7];
  const float* conv1d_w  = (const float*)d_in[8];
  const float* conv1d_b  = (const float*)d_in[9];
  const float* dt_bias   = (const float*)d_in[10];
  const float* A_log     = (const float*)d_in[11];
  const float* Dp        = (const float*)d_in[12];
  const float* norm_w    = (const float*)d_in[13];
  const float* out_proj_w= (const float*)d_in[14];
  const float* final_w   = (const float*)d_in[15];
  const float* final_b   = (const float*)d_in[16];
  float* out = (float*)d_out;

  char* Wb = (char*)d_ws;
  float* h_buf = (float*)(Wb + 0);
  bf16*  winb  = (bf16*)(Wb + 0);
  bf16*  woutb = (bf16*)(Wb + 0);
  bf16*  wfinb = (bf16*)(Wb + 262144);
  bf16*  xpost = (bf16*)(Wb + 0);
  float2* part = (float2*)(Wb + 50331648);
  bf16*  tok   = (bf16*)(Wb + 50331648);
  bf16*  zbuf  = (bf16*)(Wb + 67108864);
  bf16*  xpre  = (bf16*)(Wb + 100663296);
  bf16*  ysb   = (bf16*)(Wb + 100663296);
  bf16*  Sst   = (bf16*)(Wb + 134217728);
  float* dtv   = (float*)(Wb + 134217728 + 33554432);
  float* dAv   = dtv + 262144;
  float* stats = dAv + 262144;
  const size_t NEED = 134217728ull + 33554432 + 2097152 + 256;
  if (ws_size < NEED) {
    hipMemsetAsync(d_out, 0, (size_t)out_size*sizeof(float), stream);
    return;
  }

  k_conv1<<<dim3((B_*CMID*HMID*WMID)/256), dim3(256), 0, stream>>>(x, conv_w, conv_b, h_buf);
  k_bnstatsA<<<dim3(512), dim3(256), 0, stream>>>(h_buf, part);
  k_bnstatsB<<<dim3(1), dim3(64), 0, stream>>>(part, stats);
  k_patch<<<dim3(MTOK/8), dim3(256), 0, stream>>>(h_buf, patch_w, patch_b, stats, bn_gamma, bn_beta, tok);
  k_cvtw<<<dim3((NPADIN*DM)/256), dim3(256), 0, stream>>>(in_proj_w, winb, PROJ, 8, NPADIN*DM);
  k_mgemm<0><<<dim3(MTOK/256, NPADIN/128), dim3(512), 0, stream>>>(tok, winb, DM,
      zbuf, xpre, nullptr, nullptr, dt_bias, A_log, dtv, dAv, nullptr, nullptr);
  k_conv1d<<<dim3((MTOK/8*96)/256), dim3(256), 0, stream>>>(xpre, conv1d_w, conv1d_b, xpost);
  k_ssd1<<<dim3(B_*NH*NCH), dim3(512), 0, stream>>>(xpost, dtv, A_log, ysb, Sst);
  k_scan2<NCH,QCH><<<dim3(B_*NH*4), dim3(256), 0, stream>>>(Sst, dAv);
  k_ssd3<<<dim3(B_*NH*NCH), dim3(256), 0, stream>>>(xpost, dtv, A_log, Sst, ysb);
  k_combine<<<dim3(MTOK), dim3(256), 0, stream>>>(ysb, xpost, zbuf, Dp, norm_w);
  k_cvtw<<<dim3((DM*DI)/256), dim3(256), 0, stream>>>(out_proj_w, woutb, DM, 9, DM*DI);
  k_cvtw<<<dim3((128*DM)/256), dim3(256), 0, stream>>>(final_w, wfinb, 64, 8, 128*DM);
  k_mgemm12<<<dim3(MTOK/128), dim3(512), 0, stream>>>(ysb, woutb, tok, wfinb, final_b, out);
}